// Round 9
// baseline (362.869 us; speedup 1.0000x reference)
//
#include <hip/hip_runtime.h>
#include <stdint.h>

typedef unsigned short bf16u;
typedef float f32x4 __attribute__((ext_vector_type(4)));
typedef short bf16x8 __attribute__((ext_vector_type(8)));
typedef float f4 __attribute__((ext_vector_type(4)));

#define AS1 __attribute__((address_space(1)))
#define AS3 __attribute__((address_space(3)))

__device__ __forceinline__ float b2f(bf16u u) {
  union { uint32_t i; float f; } v; v.i = ((uint32_t)u) << 16; return v.f;
}
__device__ __forceinline__ uint32_t f2b(float f) {
  union { float f; uint32_t i; } v; v.f = f;
  uint32_t i = v.i;
  return (i + 0x7FFFu + ((i >> 16) & 1u)) >> 16; // RNE
}
__device__ __forceinline__ float sigm(float x) { return 1.f / (1.f + __expf(-x)); }
__device__ __forceinline__ float ftanh(float x) {
  float e = __expf(2.f * x);
  return 1.f - 2.f / (e + 1.f);
}
__device__ __forceinline__ uint4 pack8(f4 a, f4 b) {
  uint4 o;
  o.x = (f2b(a[0]) & 0xffffu) | (f2b(a[1]) << 16);
  o.y = (f2b(a[2]) & 0xffffu) | (f2b(a[3]) << 16);
  o.z = (f2b(b[0]) & 0xffffu) | (f2b(b[1]) << 16);
  o.w = (f2b(b[2]) & 0xffffu) | (f2b(b[3]) << 16);
  return o;
}

// ---------------- multi-segment fp32->bf16 / fp32 copy (once) ----------
struct CvtSeg { const float* src; char* dst; int blk0; int count; int tobf16; };
struct CvtArgs { CvtSeg s[12]; int nseg; };

__global__ __launch_bounds__(256)
void cvt_multi(CvtArgs a) {
  int b = blockIdx.x, seg = 0;
  while (seg + 1 < a.nseg && b >= a.s[seg + 1].blk0) ++seg;
  const CvtSeg& S = a.s[seg];
  size_t idx = ((size_t)(b - S.blk0) * 2048) + (size_t)threadIdx.x * 8;
  if ((long long)idx >= S.count) return;
  f4 x = *(const f4*)&S.src[idx];
  f4 y = *(const f4*)&S.src[idx + 4];
  if (S.tobf16) {
    *(uint4*)((bf16u*)S.dst + idx) = pack8(x, y);
  } else {
    *(f4*)((float*)S.dst + idx) = x;
    *(f4*)((float*)S.dst + idx + 4) = y;
  }
}

// ---------------- i2d GEMM: h1 = relu(x @ i2d_w^T + b) ----------------
// M=Bc N=1024 K=512.  64x128 tile, 4 waves (2Mx2N), wave tile 32x64.
// A reg-staged from f32 x (pack to bf16 in-kernel, swizzled ds_write);
// B async global_load_lds of pre-cvt bf16 weights.  Row-XOR swizzle.
__global__ __launch_bounds__(256)
void gemm_i2d(const float* __restrict__ xf, const bf16u* __restrict__ W,
              const float* __restrict__ bias, bf16u* __restrict__ Cout) {
  constexpr int K = 512, N = 1024;
  __shared__ bf16u sA[64 * 64];
  __shared__ bf16u sB[128 * 64];
  const int tid = threadIdx.x, wave = tid >> 6, lane = tid & 63;
  const int bn = blockIdx.x, bm = blockIdx.y;

  const int srA = wave * 16 + (lane >> 3);   // +8 for second slot
  const int srB = wave * 32 + (lane >> 3);
  const int kc  = (lane & 7) ^ ((lane >> 3) & 7);
  const float* gx = xf + (size_t)(bm * 64 + srA) * K + kc * 8;
  const bf16u* wg = W + (size_t)(bn * 128 + srB) * K + kc * 8;
  const int adst = srA * 64 + (lane & 7) * 8;

  const int wm = wave >> 1, wn = wave & 1;
  const int q = lane >> 4, cl = lane & 15;

  int aoff[2][2], boff[4][2];
#pragma unroll
  for (int i = 0; i < 2; ++i) {
    int m = wm * 32 + i * 16 + cl;
#pragma unroll
    for (int kk = 0; kk < 2; ++kk)
      aoff[i][kk] = m * 64 + (((q + kk * 4) ^ (m & 7)) * 8);
  }
#pragma unroll
  for (int j = 0; j < 4; ++j) {
    int n = wn * 64 + j * 16 + cl;
#pragma unroll
    for (int kk = 0; kk < 2; ++kk)
      boff[j][kk] = n * 64 + (((q + kk * 4) ^ (n & 7)) * 8);
  }

  f32x4 acc[2][4] = {};
  for (int k0 = 0; k0 < K; k0 += 64) {
    f4 a0 = *(const f4*)(gx + k0);
    f4 a1 = *(const f4*)(gx + k0 + 4);
    f4 a2 = *(const f4*)(gx + (size_t)8 * K + k0);
    f4 a3 = *(const f4*)(gx + (size_t)8 * K + k0 + 4);
#pragma unroll
    for (int t = 0; t < 4; ++t)
      __builtin_amdgcn_global_load_lds(
          (const AS1 void*)(wg + k0 + (size_t)t * 8 * K),
          (AS3 void*)&sB[wave * 2048 + t * 512], 16, 0, 0);
    *(uint4*)&sA[adst]       = pack8(a0, a1);
    *(uint4*)&sA[adst + 512] = pack8(a2, a3);
    __syncthreads();
#pragma unroll
    for (int kk = 0; kk < 2; ++kk) {
      bf16x8 af[2], bfr[4];
#pragma unroll
      for (int i = 0; i < 2; ++i) af[i] = *(const bf16x8*)&sA[aoff[i][kk]];
#pragma unroll
      for (int j = 0; j < 4; ++j) bfr[j] = *(const bf16x8*)&sB[boff[j][kk]];
#pragma unroll
      for (int i = 0; i < 2; ++i)
#pragma unroll
        for (int j = 0; j < 4; ++j)
          acc[i][j] = __builtin_amdgcn_mfma_f32_16x16x32_bf16(af[i], bfr[j], acc[i][j], 0, 0, 0);
    }
    __syncthreads();
  }

  float bv[4];
#pragma unroll
  for (int j = 0; j < 4; ++j)
    bv[j] = bias[bn * 128 + wn * 64 + j * 16 + cl];

  const int row0 = bm * 64 + wm * 32 + q * 4;
  const int col0 = bn * 128 + wn * 64 + cl;
#pragma unroll
  for (int i = 0; i < 2; ++i)
#pragma unroll
    for (int j = 0; j < 4; ++j)
#pragma unroll
      for (int r = 0; r < 4; ++r) {
        float v = fmaxf(acc[i][j][r] + bv[j], 0.f);
        Cout[(size_t)(row0 + i * 16 + r) * N + (col0 + j * 16)] = (bf16u)f2b(v);
      }
}

// -------- fused gates GEMM + GRU cell, BK=32 double-buffered ----------
// Block: 128 rows x 64 h-cols, 8 waves (4Mx2N), wave tile 32x32.
// 6 acc tiles: p=0..2 inp@w_ih^T (r,z,n); p=3..5 hprevb@w_hh^T.
// LDS: 2 buffers x 40KB (rows: [0,128)=inp, [128,256)=h, [256,640)=W
// panels, each row = 32 bf16).  Swizzle: 16B slot s of LDS row R holds
// k-chunk s^(R&3); reader uses q^(R&3).  Pipeline: iter t stages tile t+1
// into buf (t+1)&1 (computed at t-1, barrier-drained -> WAR-safe), then
// vmcnt(5) keeps those 5 loads in flight while tile t computes.  Never
// vmcnt(0) until the last tile.
template <int LAST>
__global__ __launch_bounds__(512)
void gru_fused(const bf16u* __restrict__ inp, const bf16u* __restrict__ hpb,
               const bf16u* __restrict__ wih, const bf16u* __restrict__ whh,
               const float* __restrict__ bih, const float* __restrict__ bhh,
               const float* __restrict__ hpf, float* __restrict__ hid_out,
               bf16u* __restrict__ nxt) {
  constexpr int K = 1024;
  constexpr int NT = K / 32;
  __shared__ bf16u s[2][640 * 32];   // 2 x 40 KB
  const int tid  = threadIdx.x;
  const int wave = tid >> 6;
  const int lane = tid & 63;
  const int bn = blockIdx.x, bm = blockIdx.y;   // bn: hcol block (16), bm: rows
  const int c0 = bn * 64;

  // staging: rr2 = LDS row within 128-row load unit, slot = 16B slot
  const int rr2  = tid >> 2;                // 0..127
  const int slot = tid & 3;
  const int kc   = slot ^ (rr2 & 3);
  const int dst0 = rr2 * 32 + slot * 8;
  const bf16u* gI = inp + (size_t)(bm * 128 + rr2) * K + kc * 8;
  const bf16u* gH = hpb + (size_t)(bm * 128 + rr2) * K + kc * 8;
  const bf16u* gWl[3];
  {
    const int pr = rr2 & 63, hi = rr2 >> 6;
#pragma unroll
    for (int L = 0; L < 3; ++L) {
      const int pidx = L * 2 + hi;          // panel 0..5
      const bf16u* base = (pidx < 3) ? wih : whh;
      gWl[L] = base + (size_t)((pidx % 3) * 1024 + c0 + pr) * K + kc * 8;
    }
  }

  const int wm = wave >> 1, wn = wave & 1;  // 4 row-waves x 2 col-waves
  const int q = lane >> 4, cl = lane & 15;

  int aoff[2], boff[6][2];
#pragma unroll
  for (int i = 0; i < 2; ++i) {
    const int ai = wm * 32 + i * 16 + cl;
    aoff[i] = ai * 32 + ((q ^ (ai & 3)) * 8);
  }
#pragma unroll
  for (int p = 0; p < 6; ++p)
#pragma unroll
    for (int j = 0; j < 2; ++j) {
      const int br = wn * 32 + j * 16 + cl;
      boff[p][j] = 8192 + (p * 64 + br) * 32 + ((q ^ (br & 3)) * 8);
    }

  f32x4 acc[6][2][2] = {};

#define STG(buf, t)                                                           \
  do {                                                                        \
    __builtin_amdgcn_global_load_lds((const AS1 void*)(gI + (t) * 32),        \
        (AS3 void*)&s[buf][dst0], 16, 0, 0);                                  \
    __builtin_amdgcn_global_load_lds((const AS1 void*)(gH + (t) * 32),        \
        (AS3 void*)&s[buf][4096 + dst0], 16, 0, 0);                           \
    _Pragma("unroll")                                                         \
    for (int L = 0; L < 3; ++L)                                               \
      __builtin_amdgcn_global_load_lds((const AS1 void*)(gWl[L] + (t) * 32),  \
          (AS3 void*)&s[buf][8192 + L * 4096 + dst0], 16, 0, 0);              \
  } while (0)

  STG(0, 0);
  for (int t = 0; t < NT; ++t) {
    const int cb = t & 1;
    if (t + 1 < NT) {
      STG(cb ^ 1, t + 1);
      asm volatile("s_waitcnt vmcnt(5)" ::: "memory");
    } else {
      asm volatile("s_waitcnt vmcnt(0)" ::: "memory");
    }
    __builtin_amdgcn_s_barrier();
    asm volatile("" ::: "memory");
    bf16x8 aI[2], aH[2];
#pragma unroll
    for (int i = 0; i < 2; ++i) {
      aI[i] = *(const bf16x8*)&s[cb][aoff[i]];
      aH[i] = *(const bf16x8*)&s[cb][aoff[i] + 4096];
    }
    __builtin_amdgcn_s_setprio(1);
#pragma unroll
    for (int p = 0; p < 6; ++p) {
      bf16x8 b0 = *(const bf16x8*)&s[cb][boff[p][0]];
      bf16x8 b1 = *(const bf16x8*)&s[cb][boff[p][1]];
      if (p < 3) {
        acc[p][0][0] = __builtin_amdgcn_mfma_f32_16x16x32_bf16(aI[0], b0, acc[p][0][0], 0, 0, 0);
        acc[p][0][1] = __builtin_amdgcn_mfma_f32_16x16x32_bf16(aI[0], b1, acc[p][0][1], 0, 0, 0);
        acc[p][1][0] = __builtin_amdgcn_mfma_f32_16x16x32_bf16(aI[1], b0, acc[p][1][0], 0, 0, 0);
        acc[p][1][1] = __builtin_amdgcn_mfma_f32_16x16x32_bf16(aI[1], b1, acc[p][1][1], 0, 0, 0);
      } else {
        acc[p][0][0] = __builtin_amdgcn_mfma_f32_16x16x32_bf16(aH[0], b0, acc[p][0][0], 0, 0, 0);
        acc[p][0][1] = __builtin_amdgcn_mfma_f32_16x16x32_bf16(aH[0], b1, acc[p][0][1], 0, 0, 0);
        acc[p][1][0] = __builtin_amdgcn_mfma_f32_16x16x32_bf16(aH[1], b0, acc[p][1][0], 0, 0, 0);
        acc[p][1][1] = __builtin_amdgcn_mfma_f32_16x16x32_bf16(aH[1], b1, acc[p][1][1], 0, 0, 0);
      }
    }
    __builtin_amdgcn_s_setprio(0);
    __builtin_amdgcn_s_barrier();
    asm volatile("" ::: "memory");
  }
#undef STG

  float bI[3][2], bH[3][2];
#pragma unroll
  for (int g = 0; g < 3; ++g)
#pragma unroll
    for (int j = 0; j < 2; ++j) {
      int col = c0 + wn * 32 + j * 16 + cl;
      bI[g][j] = bih[g * 1024 + col];
      bH[g][j] = bhh[g * 1024 + col];
    }

#pragma unroll
  for (int i = 0; i < 2; ++i)
#pragma unroll
    for (int j = 0; j < 2; ++j)
#pragma unroll
      for (int r_ = 0; r_ < 4; ++r_) {
        int row = bm * 128 + wm * 32 + i * 16 + q * 4 + r_;
        int col = c0 + wn * 32 + j * 16 + cl;
        size_t o = (size_t)row * 1024 + col;
        float vir = acc[0][i][j][r_] + bI[0][j];
        float viz = acc[1][i][j][r_] + bI[1][j];
        float vin = acc[2][i][j][r_] + bI[2][j];
        float vhr = acc[3][i][j][r_] + bH[0][j];
        float vhz = acc[4][i][j][r_] + bH[1][j];
        float vhn = acc[5][i][j][r_] + bH[2][j];
        float rg = sigm(vir + vhr);
        float zg = sigm(viz + vhz);
        float ng = ftanh(vin + rg * vhn);
        float hnew = (1.f - zg) * ng + zg * hpf[o];
        hid_out[o] = hnew;
        nxt[o] = (bf16u)f2b(LAST ? ftanh(hnew) : hnew);
      }
}

// ---------------- heads GEMM, 128-row tile, fused softplus + pi-softmax --
// A[M,1024] @ Wp[2304,1024]^T, Wp rows packed [mu(768)|sg(768)|pi(768)].
// Block: 128 rows, 8 waves (4Mx2N), 512 thr.  bn<12: 128x128 tile over
// packed cols (head = bn/6).  bn in [12,16): pi block o0=(bn-12)*64;
// B = 192 rows covering cols {1536 + g*256 + o0 + [0,64)}, g=0,1,2; each
// thread holds all 3 g-values -> in-register softmax epilogue.
__global__ __launch_bounds__(512)
void gemm_heads3(const bf16u* __restrict__ A, const bf16u* __restrict__ Wp,
                 const float* __restrict__ biasp, float* __restrict__ out_mu,
                 float* __restrict__ out_sg, float* __restrict__ out_pi) {
  constexpr int K = 1024;
  __shared__ bf16u s[320 * 64];     // 40 KB
  const int tid = threadIdx.x, wave = tid >> 6, lane = tid & 63;
  const int bn = blockIdx.x, bm = blockIdx.y;
  const bool ispi = (bn >= 12);
  const int o0 = (bn - 12) * 64;
  const int nbt = ispi ? 3 : 2;     // B regions of 64 rows
  const int nj  = ispi ? 6 : 4;     // B fragment panels

  const int rr  = tid >> 3;                 // 0..63
  const int kc  = (tid & 7) ^ (rr & 7);
  const int dst0 = rr * 64 + (tid & 7) * 8;
  const bf16u* gA = A + (size_t)(bm * 128 + rr) * K + kc * 8;
  const bf16u* gB[3];
#pragma unroll
  for (int t = 0; t < 3; ++t) {
    int wrow = ispi ? (1536 + t * 256 + o0 + rr) : (bn * 128 + t * 64 + rr);
    gB[t] = Wp + (size_t)wrow * K + kc * 8;
  }

  const int wm = wave >> 1, wn = wave & 1;
  const int q = lane >> 4, cl = lane & 15;

  int aoff[2][2], boff[6][2];
#pragma unroll
  for (int i = 0; i < 2; ++i) {
    int m = wm * 32 + i * 16 + cl;
#pragma unroll
    for (int kk = 0; kk < 2; ++kk)
      aoff[i][kk] = m * 64 + (((q + kk * 4) ^ (m & 7)) * 8);
  }
#pragma unroll
  for (int j = 0; j < 6; ++j) {
    int l = ispi ? ((j >> 1) * 64 + wn * 32 + (j & 1) * 16 + cl)
                 : (wn * 64 + (j & 3) * 16 + cl);
#pragma unroll
    for (int kk = 0; kk < 2; ++kk)
      boff[j][kk] = 8192 + l * 64 + (((q + kk * 4) ^ (l & 7)) * 8);
  }

  f32x4 acc[2][6] = {};
  for (int k0 = 0; k0 < K; k0 += 64) {
    __builtin_amdgcn_global_load_lds((const AS1 void*)(gA + k0),
        (AS3 void*)&s[dst0], 16, 0, 0);
    __builtin_amdgcn_global_load_lds((const AS1 void*)(gA + k0 + (size_t)64 * K),
        (AS3 void*)&s[dst0 + 4096], 16, 0, 0);
#pragma unroll
    for (int t = 0; t < 3; ++t)
      if (t < nbt)
        __builtin_amdgcn_global_load_lds((const AS1 void*)(gB[t] + k0),
            (AS3 void*)&s[8192 + dst0 + t * 4096], 16, 0, 0);
    __syncthreads();
#pragma unroll
    for (int kk = 0; kk < 2; ++kk) {
      bf16x8 af[2];
#pragma unroll
      for (int i = 0; i < 2; ++i) af[i] = *(const bf16x8*)&s[aoff[i][kk]];
#pragma unroll
      for (int j = 0; j < 6; ++j) {
        if (j >= nj) continue;
        bf16x8 bf_ = *(const bf16x8*)&s[boff[j][kk]];
#pragma unroll
        for (int i = 0; i < 2; ++i)
          acc[i][j] = __builtin_amdgcn_mfma_f32_16x16x32_bf16(af[i], bf_, acc[i][j], 0, 0, 0);
      }
    }
    __syncthreads();
  }

  const int row0 = bm * 128 + wm * 32 + q * 4;
  if (!ispi) {
    float bv[4];
#pragma unroll
    for (int j = 0; j < 4; ++j)
      bv[j] = biasp[bn * 128 + wn * 64 + j * 16 + cl];
    const int head = bn / 6;
    const int ch0 = (bn % 6) * 128 + wn * 64 + cl;
#pragma unroll
    for (int i = 0; i < 2; ++i)
#pragma unroll
      for (int j = 0; j < 4; ++j)
#pragma unroll
        for (int r = 0; r < 4; ++r) {
          float v = acc[i][j][r] + bv[j];
          size_t off = (size_t)(row0 + i * 16 + r) * 768 + (ch0 + j * 16);
          if (head == 0) out_mu[off] = v;
          else out_sg[off] = fmaxf(v, 0.f) + __logf(1.f + __expf(-fabsf(v)));
        }
  } else {
    float bv[6];
#pragma unroll
    for (int j = 0; j < 6; ++j)
      bv[j] = biasp[1536 + (j >> 1) * 256 + o0 + wn * 32 + (j & 1) * 16 + cl];
#pragma unroll
    for (int i = 0; i < 2; ++i)
#pragma unroll
      for (int jo = 0; jo < 2; ++jo)
#pragma unroll
        for (int r = 0; r < 4; ++r) {
          float v0 = acc[i][jo][r]     + bv[jo];
          float v1 = acc[i][2 + jo][r] + bv[2 + jo];
          float v2 = acc[i][4 + jo][r] + bv[4 + jo];
          float m = fmaxf(fmaxf(v0, v1), v2);
          float e0 = __expf(v0 - m), e1 = __expf(v1 - m), e2 = __expf(v2 - m);
          float sc = 1.f / (e0 + e1 + e2);
          size_t base = (size_t)(row0 + i * 16 + r) * 768
                        + (o0 + wn * 32 + jo * 16 + cl);
          out_pi[base]       = e0 * sc;
          out_pi[base + 256] = e1 * sc;
          out_pi[base + 512] = e2 * sc;
        }
  }
}

extern "C" void kernel_launch(void* const* d_in, const int* in_sizes, int n_in,
                              void* d_out, int out_size, void* d_ws, size_t ws_size,
                              hipStream_t stream) {
  const float* x      = (const float*)d_in[0];
  const float* hidden = (const float*)d_in[1];   // [2][4096][1024]
  const float* i2d_w  = (const float*)d_in[2];
  const float* i2d_b  = (const float*)d_in[3];
  const float* w_ih   = (const float*)d_in[4];   // [2][3072][1024]
  const float* w_hh   = (const float*)d_in[5];
  const float* b_ih   = (const float*)d_in[6];
  const float* b_hh   = (const float*)d_in[7];
  const float* mu_w   = (const float*)d_in[8];
  const float* mu_b   = (const float*)d_in[9];
  const float* sg_w   = (const float*)d_in[10];
  const float* sg_b   = (const float*)d_in[11];
  const float* pi_w   = (const float*)d_in[12];
  const float* pi_b   = (const float*)d_in[13];
  float* out = (float*)d_out;

  const size_t BH = 4194304;      // 4096*1024
  const int HS = 3145728;         // 4096*768
  float* hid_base = out + (size_t)3 * HS;

  dim3 blk(256, 1, 1);

  // ---- ws: bf16 weights (29.5 MB) + packed head bias fp32 + hidden bf16 --
  bf16u* wb_i2d = (bf16u*)d_ws;             // 524288
  bf16u* wb_ih  = wb_i2d + 524288;          // 6291456 (both layers)
  bf16u* wb_hh  = wb_ih + 6291456;          // 6291456
  bf16u* wb_hd  = wb_hh + 6291456;          // 2359296 packed [mu|sg|pi][768][1024]
  float* biasp  = (float*)((char*)d_ws + 30932992);  // 2304 fp32
  const size_t wbytes = 30942208;

  // hidden bf16 (both layers), launch-invariant -> converted once
  bf16u* hb0 = (bf16u*)((char*)d_ws + wbytes);       // 4194304 elems
  bf16u* hb1 = hb0 + BH;                             // 4194304 elems
  const size_t hbbytes = (size_t)2 * BH * 2;         // 16 MB

  { // one dispatch: 6 weight cvts + 3 bias copies + hidden cvt
    CvtArgs a{};
    int nb = 0;
    auto seg = [&](const float* s, void* d, int count, int tobf) {
      a.s[a.nseg++] = {s, (char*)d, nb, count, tobf};
      nb += (count + 2047) / 2048;
    };
    seg(i2d_w, wb_i2d, 524288, 1);
    seg(w_ih,  wb_ih, 6291456, 1);
    seg(w_hh,  wb_hh, 6291456, 1);
    seg(mu_w,  wb_hd, 786432, 1);
    seg(sg_w,  wb_hd + 786432, 786432, 1);
    seg(pi_w,  wb_hd + 1572864, 786432, 1);
    seg(mu_b,  biasp, 768, 0);
    seg(sg_b,  biasp + 768, 768, 0);
    seg(pi_b,  biasp + 1536, 768, 0);
    seg(hidden, hb0, 8388608, 1);   // both layers, contiguous
    cvt_multi<<<dim3(nb), blk, 0, stream>>>(a);
  }

  // ---- per-chunk scratch: Bc*4096 B (ws0 + nxt0) ----
  int Bc = 4096;
  while (wbytes + hbbytes + (size_t)Bc * 4096 > ws_size && Bc > 256) Bc >>= 1;
  const int nchunk = 4096 / Bc;

  char* cbase = (char*)d_ws + wbytes + hbbytes;
  bf16u* ws0  = (bf16u*)cbase;                          // h1 / layer1 nxt bf16
  bf16u* nxt0 = (bf16u*)(cbase + (size_t)Bc * 2048);    // layer0 nxt bf16

  for (int c = 0; c < nchunk; ++c) {
    const size_t off = (size_t)c * Bc;
    const float* h0_c = hidden + off * 1024;
    const float* h1_c = hidden + BH + off * 1024;

    // h1 = relu(x @ i2d_w^T + b); x read f32 directly (in-kernel cvt)
    gemm_i2d<<<dim3(8, Bc / 64), blk, 0, stream>>>(
        x + off * 512, wb_i2d, i2d_b, ws0);
    // layer 0: fused gates GEMM + GRU cell (BK=32 double-buffered)
    gru_fused<0><<<dim3(16, Bc / 128), dim3(512, 1, 1), 0, stream>>>(
        ws0, hb0 + off * 1024, wb_ih, wb_hh, b_ih, b_hh, h0_c,
        hid_base + off * 1024, nxt0);
    // layer 1
    gru_fused<1><<<dim3(16, Bc / 128), dim3(512, 1, 1), 0, stream>>>(
        nxt0, hb1 + off * 1024, wb_ih + 3145728, wb_hh + 3145728,
        b_ih + 3072, b_hh + 3072, h1_c, hid_base + BH + off * 1024, ws0);
    // heads: mu/softplus(sg) direct + fused pi softmax, 128-row tiles
    gemm_heads3<<<dim3(16, Bc / 128), dim3(512, 1, 1), 0, stream>>>(
        ws0, wb_hd, biasp, out + off * 768, out + HS + off * 768,
        out + 2 * (size_t)HS + off * 768);
  }
}

// Round 10
// 346.683 us; speedup vs baseline: 1.0467x; 1.0467x over previous
//
#include <hip/hip_runtime.h>
#include <stdint.h>

typedef unsigned short bf16u;
typedef float f32x4 __attribute__((ext_vector_type(4)));
typedef short bf16x8 __attribute__((ext_vector_type(8)));
typedef float f4 __attribute__((ext_vector_type(4)));

#define AS1 __attribute__((address_space(1)))
#define AS3 __attribute__((address_space(3)))

__device__ __forceinline__ float b2f(bf16u u) {
  union { uint32_t i; float f; } v; v.i = ((uint32_t)u) << 16; return v.f;
}
__device__ __forceinline__ uint32_t f2b(float f) {
  union { float f; uint32_t i; } v; v.f = f;
  uint32_t i = v.i;
  return (i + 0x7FFFu + ((i >> 16) & 1u)) >> 16; // RNE
}
__device__ __forceinline__ float sigm(float x) { return 1.f / (1.f + __expf(-x)); }
__device__ __forceinline__ float ftanh(float x) {
  float e = __expf(2.f * x);
  return 1.f - 2.f / (e + 1.f);
}
__device__ __forceinline__ uint4 pack8(f4 a, f4 b) {
  uint4 o;
  o.x = (f2b(a[0]) & 0xffffu) | (f2b(a[1]) << 16);
  o.y = (f2b(a[2]) & 0xffffu) | (f2b(a[3]) << 16);
  o.z = (f2b(b[0]) & 0xffffu) | (f2b(b[1]) << 16);
  o.w = (f2b(b[2]) & 0xffffu) | (f2b(b[3]) << 16);
  return o;
}

// ---------------- multi-segment fp32->bf16 / fp32 copy (once) ----------
struct CvtSeg { const float* src; char* dst; int blk0; int count; int tobf16; };
struct CvtArgs { CvtSeg s[12]; int nseg; };

__global__ __launch_bounds__(256)
void cvt_multi(CvtArgs a) {
  int b = blockIdx.x, seg = 0;
  while (seg + 1 < a.nseg && b >= a.s[seg + 1].blk0) ++seg;
  const CvtSeg& S = a.s[seg];
  size_t idx = ((size_t)(b - S.blk0) * 2048) + (size_t)threadIdx.x * 8;
  if ((long long)idx >= S.count) return;
  f4 x = *(const f4*)&S.src[idx];
  f4 y = *(const f4*)&S.src[idx + 4];
  if (S.tobf16) {
    *(uint4*)((bf16u*)S.dst + idx) = pack8(x, y);
  } else {
    *(f4*)((float*)S.dst + idx) = x;
    *(f4*)((float*)S.dst + idx + 4) = y;
  }
}

// ---------------- i2d GEMM: h1 = relu(x @ i2d_w^T + b) ----------------
// M=Bc N=1024 K=512.  64x128 tile, 4 waves (2Mx2N), wave tile 32x64.
// A reg-staged from f32 x (pack to bf16 in-kernel, swizzled ds_write);
// B async global_load_lds of pre-cvt bf16 weights.  Row-XOR swizzle.
__global__ __launch_bounds__(256)
void gemm_i2d(const float* __restrict__ xf, const bf16u* __restrict__ W,
              const float* __restrict__ bias, bf16u* __restrict__ Cout) {
  constexpr int K = 512, N = 1024;
  __shared__ bf16u sA[64 * 64];
  __shared__ bf16u sB[128 * 64];
  const int tid = threadIdx.x, wave = tid >> 6, lane = tid & 63;
  const int bn = blockIdx.x, bm = blockIdx.y;

  const int srA = wave * 16 + (lane >> 3);   // +8 for second slot
  const int srB = wave * 32 + (lane >> 3);
  const int kc  = (lane & 7) ^ ((lane >> 3) & 7);
  const float* gx = xf + (size_t)(bm * 64 + srA) * K + kc * 8;
  const bf16u* wg = W + (size_t)(bn * 128 + srB) * K + kc * 8;
  const int adst = srA * 64 + (lane & 7) * 8;

  const int wm = wave >> 1, wn = wave & 1;
  const int q = lane >> 4, cl = lane & 15;

  int aoff[2][2], boff[4][2];
#pragma unroll
  for (int i = 0; i < 2; ++i) {
    int m = wm * 32 + i * 16 + cl;
#pragma unroll
    for (int kk = 0; kk < 2; ++kk)
      aoff[i][kk] = m * 64 + (((q + kk * 4) ^ (m & 7)) * 8);
  }
#pragma unroll
  for (int j = 0; j < 4; ++j) {
    int n = wn * 64 + j * 16 + cl;
#pragma unroll
    for (int kk = 0; kk < 2; ++kk)
      boff[j][kk] = n * 64 + (((q + kk * 4) ^ (n & 7)) * 8);
  }

  f32x4 acc[2][4] = {};
  for (int k0 = 0; k0 < K; k0 += 64) {
    f4 a0 = *(const f4*)(gx + k0);
    f4 a1 = *(const f4*)(gx + k0 + 4);
    f4 a2 = *(const f4*)(gx + (size_t)8 * K + k0);
    f4 a3 = *(const f4*)(gx + (size_t)8 * K + k0 + 4);
#pragma unroll
    for (int t = 0; t < 4; ++t)
      __builtin_amdgcn_global_load_lds(
          (const AS1 void*)(wg + k0 + (size_t)t * 8 * K),
          (AS3 void*)&sB[wave * 2048 + t * 512], 16, 0, 0);
    *(uint4*)&sA[adst]       = pack8(a0, a1);
    *(uint4*)&sA[adst + 512] = pack8(a2, a3);
    __syncthreads();
#pragma unroll
    for (int kk = 0; kk < 2; ++kk) {
      bf16x8 af[2], bfr[4];
#pragma unroll
      for (int i = 0; i < 2; ++i) af[i] = *(const bf16x8*)&sA[aoff[i][kk]];
#pragma unroll
      for (int j = 0; j < 4; ++j) bfr[j] = *(const bf16x8*)&sB[boff[j][kk]];
#pragma unroll
      for (int i = 0; i < 2; ++i)
#pragma unroll
        for (int j = 0; j < 4; ++j)
          acc[i][j] = __builtin_amdgcn_mfma_f32_16x16x32_bf16(af[i], bfr[j], acc[i][j], 0, 0, 0);
    }
    __syncthreads();
  }

  float bv[4];
#pragma unroll
  for (int j = 0; j < 4; ++j)
    bv[j] = bias[bn * 128 + wn * 64 + j * 16 + cl];

  const int row0 = bm * 64 + wm * 32 + q * 4;
  const int col0 = bn * 128 + wn * 64 + cl;
#pragma unroll
  for (int i = 0; i < 2; ++i)
#pragma unroll
    for (int j = 0; j < 4; ++j)
#pragma unroll
      for (int r = 0; r < 4; ++r) {
        float v = fmaxf(acc[i][j][r] + bv[j], 0.f);
        Cout[(size_t)(row0 + i * 16 + r) * N + (col0 + j * 16)] = (bf16u)f2b(v);
      }
}

// -------- fused gates GEMM + GRU cell, BK=32 dbuf, line-group LDS ------
// Block: 128 rows x 64 h-cols, 8 waves (4Mx2N), wave tile 32x32.
// 6 acc tiles: p=0..2 inp@w_ih^T (r,z,n); p=3..5 hprevb@w_hh^T.
// LDS: 2 buffers x 40KB.  Per buffer (elems): I [0,4096), H [4096,8192),
// W units L=0..2 [8192+L*4096, +4096) packing panels {2L, 2L+1}.
// Line-group layout (proven 0-conflict in gatesf R4): each 128B line holds
// rows {2g, 2g+1} (32 elems each); 16B slot s of line g holds
// (row = 2g + (s'>>2), chunk = s'&3), s' = s ^ (g&7).  Staging dest is
// linear (dst = tid*16B); reader slot = (((row&1)<<2)|q) ^ (g&7).
// Pipeline: iter t stages tile t+1 into buf (t+1)&1 (last computed at
// t-1, closed by that iter's barrier -> WAR-safe); vmcnt(5) keeps tile
// t+1's 5 loads in flight while tile t computes.  vmcnt(0) only at tail.
template <int LAST>
__global__ __launch_bounds__(512)
void gru_fused(const bf16u* __restrict__ inp, const bf16u* __restrict__ hpb,
               const bf16u* __restrict__ wih, const bf16u* __restrict__ whh,
               const float* __restrict__ bih, const float* __restrict__ bhh,
               const float* __restrict__ hpf, float* __restrict__ hid_out,
               bf16u* __restrict__ nxt) {
  constexpr int K = 1024;
  constexpr int NT = K / 32;         // 32 K-tiles
  __shared__ bf16u s[2][20480];      // 2 x 40 KB
  const int tid  = threadIdx.x;
  const int wave = tid >> 6;
  const int lane = tid & 63;
  const int bn = blockIdx.x, bm = blockIdx.y;   // bn: hcol block (16), bm: rows
  const int c0 = bn * 64;

  // staging decode: line sg = tid>>3, slot = tid&7; s' = slot^(sg&7);
  // row = 2*sg + (s'>>2); chunk = s'&3.  Dest is linear: tid*8 elems.
  const int sg   = tid >> 3;             // 0..63
  const int slot = tid & 7;
  const int sp   = slot ^ (sg & 7);
  const int srow = sg * 2 + (sp >> 2);   // 0..127
  const int sch  = sp & 3;
  const int dst0 = tid * 8;
  const bf16u* gI = inp + (size_t)(bm * 128 + srow) * K + sch * 8;
  const bf16u* gH = hpb + (size_t)(bm * 128 + srow) * K + sch * 8;
  const bf16u* gWl[3];
  {
    const int hi = srow >> 6, pr = srow & 63;
#pragma unroll
    for (int L = 0; L < 3; ++L) {
      const int pidx = L * 2 + hi;       // panel 0..5
      const bf16u* base = (pidx < 3) ? wih : whh;
      gWl[L] = base + (size_t)((pidx % 3) * 1024 + c0 + pr) * K + sch * 8;
    }
  }

  const int wm = wave >> 1, wn = wave & 1;  // 4 row-waves x 2 col-waves
  const int q = lane >> 4, cl = lane & 15;

  int aoff[2], boff[6][2];
#pragma unroll
  for (int i = 0; i < 2; ++i) {
    const int ai = wm * 32 + i * 16 + cl;      // 0..127
    const int ga = ai >> 1;
    aoff[i] = ga * 64 + (((((ai & 1) << 2) | q) ^ (ga & 7)) * 8);
  }
#pragma unroll
  for (int p = 0; p < 6; ++p)
#pragma unroll
    for (int j = 0; j < 2; ++j) {
      const int br = wn * 32 + j * 16 + cl;    // 0..63 within panel
      const int gu = (p & 1) * 32 + (br >> 1); // line within W unit
      boff[p][j] = 8192 + (p >> 1) * 4096 + gu * 64
                   + (((((br & 1) << 2) | q) ^ (gu & 7)) * 8);
    }

  f32x4 acc[6][2][2] = {};

#define STG(buf, t)                                                           \
  do {                                                                        \
    __builtin_amdgcn_global_load_lds((const AS1 void*)(gI + (t) * 32),        \
        (AS3 void*)&s[buf][dst0], 16, 0, 0);                                  \
    __builtin_amdgcn_global_load_lds((const AS1 void*)(gH + (t) * 32),        \
        (AS3 void*)&s[buf][4096 + dst0], 16, 0, 0);                           \
    _Pragma("unroll")                                                         \
    for (int L = 0; L < 3; ++L)                                               \
      __builtin_amdgcn_global_load_lds((const AS1 void*)(gWl[L] + (t) * 32),  \
          (AS3 void*)&s[buf][8192 + L * 4096 + dst0], 16, 0, 0);              \
  } while (0)

  STG(0, 0);
  for (int t = 0; t < NT; ++t) {
    const int cb = t & 1;
    if (t + 1 < NT) {
      STG(cb ^ 1, t + 1);
      asm volatile("s_waitcnt vmcnt(5)" ::: "memory");   // tile t landed
    } else {
      asm volatile("s_waitcnt vmcnt(0)" ::: "memory");
    }
    __builtin_amdgcn_s_barrier();
    asm volatile("" ::: "memory");
    bf16x8 aI[2], aH[2];
#pragma unroll
    for (int i = 0; i < 2; ++i) {
      aI[i] = *(const bf16x8*)&s[cb][aoff[i]];
      aH[i] = *(const bf16x8*)&s[cb][aoff[i] + 4096];
    }
    __builtin_amdgcn_s_setprio(1);
#pragma unroll
    for (int p = 0; p < 6; ++p) {
      bf16x8 b0 = *(const bf16x8*)&s[cb][boff[p][0]];
      bf16x8 b1 = *(const bf16x8*)&s[cb][boff[p][1]];
      if (p < 3) {
        acc[p][0][0] = __builtin_amdgcn_mfma_f32_16x16x32_bf16(aI[0], b0, acc[p][0][0], 0, 0, 0);
        acc[p][0][1] = __builtin_amdgcn_mfma_f32_16x16x32_bf16(aI[0], b1, acc[p][0][1], 0, 0, 0);
        acc[p][1][0] = __builtin_amdgcn_mfma_f32_16x16x32_bf16(aI[1], b0, acc[p][1][0], 0, 0, 0);
        acc[p][1][1] = __builtin_amdgcn_mfma_f32_16x16x32_bf16(aI[1], b1, acc[p][1][1], 0, 0, 0);
      } else {
        acc[p][0][0] = __builtin_amdgcn_mfma_f32_16x16x32_bf16(aH[0], b0, acc[p][0][0], 0, 0, 0);
        acc[p][0][1] = __builtin_amdgcn_mfma_f32_16x16x32_bf16(aH[0], b1, acc[p][0][1], 0, 0, 0);
        acc[p][1][0] = __builtin_amdgcn_mfma_f32_16x16x32_bf16(aH[1], b0, acc[p][1][0], 0, 0, 0);
        acc[p][1][1] = __builtin_amdgcn_mfma_f32_16x16x32_bf16(aH[1], b1, acc[p][1][1], 0, 0, 0);
      }
    }
    __builtin_amdgcn_s_setprio(0);
    __builtin_amdgcn_s_barrier();
    asm volatile("" ::: "memory");
  }
#undef STG

  float bI[3][2], bH[3][2];
#pragma unroll
  for (int g = 0; g < 3; ++g)
#pragma unroll
    for (int j = 0; j < 2; ++j) {
      int col = c0 + wn * 32 + j * 16 + cl;
      bI[g][j] = bih[g * 1024 + col];
      bH[g][j] = bhh[g * 1024 + col];
    }

#pragma unroll
  for (int i = 0; i < 2; ++i)
#pragma unroll
    for (int j = 0; j < 2; ++j)
#pragma unroll
      for (int r_ = 0; r_ < 4; ++r_) {
        int row = bm * 128 + wm * 32 + i * 16 + q * 4 + r_;
        int col = c0 + wn * 32 + j * 16 + cl;
        size_t o = (size_t)row * 1024 + col;
        float vir = acc[0][i][j][r_] + bI[0][j];
        float viz = acc[1][i][j][r_] + bI[1][j];
        float vin = acc[2][i][j][r_] + bI[2][j];
        float vhr = acc[3][i][j][r_] + bH[0][j];
        float vhz = acc[4][i][j][r_] + bH[1][j];
        float vhn = acc[5][i][j][r_] + bH[2][j];
        float rg = sigm(vir + vhr);
        float zg = sigm(viz + vhz);
        float ng = ftanh(vin + rg * vhn);
        float hnew = (1.f - zg) * ng + zg * hpf[o];
        hid_out[o] = hnew;
        nxt[o] = (bf16u)f2b(LAST ? ftanh(hnew) : hnew);
      }
}

// ---------------- heads GEMM, 128-row tile, fused softplus + pi-softmax --
// A[M,1024] @ Wp[2304,1024]^T, Wp rows packed [mu(768)|sg(768)|pi(768)].
// Block: 128 rows, 8 waves (4Mx2N), 512 thr.  bn<12: 128x128 tile over
// packed cols (head = bn/6).  bn in [12,16): pi block o0=(bn-12)*64;
// B = 192 rows covering cols {1536 + g*256 + o0 + [0,64)}, g=0,1,2; each
// thread holds all 3 g-values -> in-register softmax epilogue.
__global__ __launch_bounds__(512)
void gemm_heads3(const bf16u* __restrict__ A, const bf16u* __restrict__ Wp,
                 const float* __restrict__ biasp, float* __restrict__ out_mu,
                 float* __restrict__ out_sg, float* __restrict__ out_pi) {
  constexpr int K = 1024;
  __shared__ bf16u s[320 * 64];     // 40 KB
  const int tid = threadIdx.x, wave = tid >> 6, lane = tid & 63;
  const int bn = blockIdx.x, bm = blockIdx.y;
  const bool ispi = (bn >= 12);
  const int o0 = (bn - 12) * 64;
  const int nbt = ispi ? 3 : 2;     // B regions of 64 rows
  const int nj  = ispi ? 6 : 4;     // B fragment panels

  const int rr  = tid >> 3;                 // 0..63
  const int kc  = (tid & 7) ^ (rr & 7);
  const int dst0 = rr * 64 + (tid & 7) * 8;
  const bf16u* gA = A + (size_t)(bm * 128 + rr) * K + kc * 8;
  const bf16u* gB[3];
#pragma unroll
  for (int t = 0; t < 3; ++t) {
    int wrow = ispi ? (1536 + t * 256 + o0 + rr) : (bn * 128 + t * 64 + rr);
    gB[t] = Wp + (size_t)wrow * K + kc * 8;
  }

  const int wm = wave >> 1, wn = wave & 1;
  const int q = lane >> 4, cl = lane & 15;

  int aoff[2][2], boff[6][2];
#pragma unroll
  for (int i = 0; i < 2; ++i) {
    int m = wm * 32 + i * 16 + cl;
#pragma unroll
    for (int kk = 0; kk < 2; ++kk)
      aoff[i][kk] = m * 64 + (((q + kk * 4) ^ (m & 7)) * 8);
  }
#pragma unroll
  for (int j = 0; j < 6; ++j) {
    int l = ispi ? ((j >> 1) * 64 + wn * 32 + (j & 1) * 16 + cl)
                 : (wn * 64 + (j & 3) * 16 + cl);
#pragma unroll
    for (int kk = 0; kk < 2; ++kk)
      boff[j][kk] = 8192 + l * 64 + (((q + kk * 4) ^ (l & 7)) * 8);
  }

  f32x4 acc[2][6] = {};
  for (int k0 = 0; k0 < K; k0 += 64) {
    __builtin_amdgcn_global_load_lds((const AS1 void*)(gA + k0),
        (AS3 void*)&s[dst0], 16, 0, 0);
    __builtin_amdgcn_global_load_lds((const AS1 void*)(gA + k0 + (size_t)64 * K),
        (AS3 void*)&s[dst0 + 4096], 16, 0, 0);
#pragma unroll
    for (int t = 0; t < 3; ++t)
      if (t < nbt)
        __builtin_amdgcn_global_load_lds((const AS1 void*)(gB[t] + k0),
            (AS3 void*)&s[8192 + dst0 + t * 4096], 16, 0, 0);
    __syncthreads();
#pragma unroll
    for (int kk = 0; kk < 2; ++kk) {
      bf16x8 af[2];
#pragma unroll
      for (int i = 0; i < 2; ++i) af[i] = *(const bf16x8*)&s[aoff[i][kk]];
#pragma unroll
      for (int j = 0; j < 6; ++j) {
        if (j >= nj) continue;
        bf16x8 bf_ = *(const bf16x8*)&s[boff[j][kk]];
#pragma unroll
        for (int i = 0; i < 2; ++i)
          acc[i][j] = __builtin_amdgcn_mfma_f32_16x16x32_bf16(af[i], bf_, acc[i][j], 0, 0, 0);
      }
    }
    __syncthreads();
  }

  const int row0 = bm * 128 + wm * 32 + q * 4;
  if (!ispi) {
    float bv[4];
#pragma unroll
    for (int j = 0; j < 4; ++j)
      bv[j] = biasp[bn * 128 + wn * 64 + j * 16 + cl];
    const int head = bn / 6;
    const int ch0 = (bn % 6) * 128 + wn * 64 + cl;
#pragma unroll
    for (int i = 0; i < 2; ++i)
#pragma unroll
      for (int j = 0; j < 4; ++j)
#pragma unroll
        for (int r = 0; r < 4; ++r) {
          float v = acc[i][j][r] + bv[j];
          size_t off = (size_t)(row0 + i * 16 + r) * 768 + (ch0 + j * 16);
          if (head == 0) out_mu[off] = v;
          else out_sg[off] = fmaxf(v, 0.f) + __logf(1.f + __expf(-fabsf(v)));
        }
  } else {
    float bv[6];
#pragma unroll
    for (int j = 0; j < 6; ++j)
      bv[j] = biasp[1536 + (j >> 1) * 256 + o0 + wn * 32 + (j & 1) * 16 + cl];
#pragma unroll
    for (int i = 0; i < 2; ++i)
#pragma unroll
      for (int jo = 0; jo < 2; ++jo)
#pragma unroll
        for (int r = 0; r < 4; ++r) {
          float v0 = acc[i][jo][r]     + bv[jo];
          float v1 = acc[i][2 + jo][r] + bv[2 + jo];
          float v2 = acc[i][4 + jo][r] + bv[4 + jo];
          float m = fmaxf(fmaxf(v0, v1), v2);
          float e0 = __expf(v0 - m), e1 = __expf(v1 - m), e2 = __expf(v2 - m);
          float sc = 1.f / (e0 + e1 + e2);
          size_t base = (size_t)(row0 + i * 16 + r) * 768
                        + (o0 + wn * 32 + jo * 16 + cl);
          out_pi[base]       = e0 * sc;
          out_pi[base + 256] = e1 * sc;
          out_pi[base + 512] = e2 * sc;
        }
  }
}

extern "C" void kernel_launch(void* const* d_in, const int* in_sizes, int n_in,
                              void* d_out, int out_size, void* d_ws, size_t ws_size,
                              hipStream_t stream) {
  const float* x      = (const float*)d_in[0];
  const float* hidden = (const float*)d_in[1];   // [2][4096][1024]
  const float* i2d_w  = (const float*)d_in[2];
  const float* i2d_b  = (const float*)d_in[3];
  const float* w_ih   = (const float*)d_in[4];   // [2][3072][1024]
  const float* w_hh   = (const float*)d_in[5];
  const float* b_ih   = (const float*)d_in[6];
  const float* b_hh   = (const float*)d_in[7];
  const float* mu_w   = (const float*)d_in[8];
  const float* mu_b   = (const float*)d_in[9];
  const float* sg_w   = (const float*)d_in[10];
  const float* sg_b   = (const float*)d_in[11];
  const float* pi_w   = (const float*)d_in[12];
  const float* pi_b   = (const float*)d_in[13];
  float* out = (float*)d_out;

  const size_t BH = 4194304;      // 4096*1024
  const int HS = 3145728;         // 4096*768
  float* hid_base = out + (size_t)3 * HS;

  dim3 blk(256, 1, 1);

  // ---- ws: bf16 weights (29.5 MB) + packed head bias fp32 + hidden bf16 --
  bf16u* wb_i2d = (bf16u*)d_ws;             // 524288
  bf16u* wb_ih  = wb_i2d + 524288;          // 6291456 (both layers)
  bf16u* wb_hh  = wb_ih + 6291456;          // 6291456
  bf16u* wb_hd  = wb_hh + 6291456;          // 2359296 packed [mu|sg|pi][768][1024]
  float* biasp  = (float*)((char*)d_ws + 30932992);  // 2304 fp32
  const size_t wbytes = 30942208;

  // hidden bf16 (both layers), launch-invariant -> converted once
  bf16u* hb0 = (bf16u*)((char*)d_ws + wbytes);       // 4194304 elems
  bf16u* hb1 = hb0 + BH;                             // 4194304 elems
  const size_t hbbytes = (size_t)2 * BH * 2;         // 16 MB

  { // one dispatch: 6 weight cvts + 3 bias copies + hidden cvt
    CvtArgs a{};
    int nb = 0;
    auto seg = [&](const float* s, void* d, int count, int tobf) {
      a.s[a.nseg++] = {s, (char*)d, nb, count, tobf};
      nb += (count + 2047) / 2048;
    };
    seg(i2d_w, wb_i2d, 524288, 1);
    seg(w_ih,  wb_ih, 6291456, 1);
    seg(w_hh,  wb_hh, 6291456, 1);
    seg(mu_w,  wb_hd, 786432, 1);
    seg(sg_w,  wb_hd + 786432, 786432, 1);
    seg(pi_w,  wb_hd + 1572864, 786432, 1);
    seg(mu_b,  biasp, 768, 0);
    seg(sg_b,  biasp + 768, 768, 0);
    seg(pi_b,  biasp + 1536, 768, 0);
    seg(hidden, hb0, 8388608, 1);   // both layers, contiguous
    cvt_multi<<<dim3(nb), blk, 0, stream>>>(a);
  }

  // ---- per-chunk scratch: Bc*4096 B (ws0 + nxt0) ----
  int Bc = 4096;
  while (wbytes + hbbytes + (size_t)Bc * 4096 > ws_size && Bc > 256) Bc >>= 1;
  const int nchunk = 4096 / Bc;

  char* cbase = (char*)d_ws + wbytes + hbbytes;
  bf16u* ws0  = (bf16u*)cbase;                          // h1 / layer1 nxt bf16
  bf16u* nxt0 = (bf16u*)(cbase + (size_t)Bc * 2048);    // layer0 nxt bf16

  for (int c = 0; c < nchunk; ++c) {
    const size_t off = (size_t)c * Bc;
    const float* h0_c = hidden + off * 1024;
    const float* h1_c = hidden + BH + off * 1024;

    // h1 = relu(x @ i2d_w^T + b); x read f32 directly (in-kernel cvt)
    gemm_i2d<<<dim3(8, Bc / 64), blk, 0, stream>>>(
        x + off * 512, wb_i2d, i2d_b, ws0);
    // layer 0: fused gates GEMM + GRU cell (BK=32 dbuf, line-group LDS)
    gru_fused<0><<<dim3(16, Bc / 128), dim3(512, 1, 1), 0, stream>>>(
        ws0, hb0 + off * 1024, wb_ih, wb_hh, b_ih, b_hh, h0_c,
        hid_base + off * 1024, nxt0);
    // layer 1
    gru_fused<1><<<dim3(16, Bc / 128), dim3(512, 1, 1), 0, stream>>>(
        nxt0, hb1 + off * 1024, wb_ih + 3145728, wb_hh + 3145728,
        b_ih + 3072, b_hh + 3072, h1_c, hid_base + BH + off * 1024, ws0);
    // heads: mu/softplus(sg) direct + fused pi softmax, 128-row tiles
    gemm_heads3<<<dim3(16, Bc / 128), dim3(512, 1, 1), 0, stream>>>(
        ws0, wb_hd, biasp, out + off * 768, out + HS + off * 768,
        out + 2 * (size_t)HS + off * 768);
  }
}